// Round 11
// baseline (1712.143 us; speedup 1.0000x reference)
//
#include <hip/hip_runtime.h>
#include <math.h>

// GPPN fused v7: B=32, L_H=128, MAZE=64, F=5, OUT=16, k=10 (9 LSTM steps)
// R10 backbone + occupancy/coalescing pass:
//  - kInit: launch_bounds (256,2)->(256,4)  (2->4 blocks/CU)
//  - kFuse: launch_bounds (256,4)->(256,6); h_old staged COALESCED into sH and
//    a-frags read from LDS (was: 16x64B fractured global reads per wave).
// Arithmetic identical to R10 => absmax must stay 6.103516e-05.

typedef _Float16 f16;
typedef _Float16 f16x4 __attribute__((ext_vector_type(4)));
typedef _Float16 f16x8 __attribute__((ext_vector_type(8)));
typedef float    f32x4 __attribute__((ext_vector_type(4)));

#define NB 32
#define HWD 64

// ---- workspace byte offsets
#define OB_CC    ((size_t)0)            // f16 c [blk][128][64]   32 MB
#define OB_HA    ((size_t)33554432)     // f16 h ping             32 MB
#define OB_HB    ((size_t)67108864)     // f16 h pong             32 MB
#define OB_DA    ((size_t)100663296)    // f16 d ping             8 MB
#define OB_DB    ((size_t)109051904)    // f16 d pong             8 MB
#define OB_WCB   ((size_t)117440512)    // f16 conv3 B-frags      589824 B
#define OB_WGB   ((size_t)118030336)    // f16 W_hh B-frags       131072 B
#define OB_WIB   ((size_t)118161408)    // f16 W_ih replicated    32768 B
#define OB_W5B   ((size_t)118194176)    // f16 W5 B-frags         8192 B
#define OB_WHB   ((size_t)118202368)    // f16 hid_w B-frags K=96 24576 B
#define OB_WPB   ((size_t)118226944)    // f16 policy B-frags     4096 B
#define OB_BS2   ((size_t)118231040)    // f32 b_ih+b_hh+cb*W_ih  2048 B
#define WS_BYTES ((size_t)118233088)

__device__ __forceinline__ float sigm(float x){ return 1.f/(1.f+__expf(-x)); }
__device__ __forceinline__ float tanhx(float x){ return 1.f - 2.f/(1.f+__expf(2.f*x)); }

// ---------------- one-time weight transforms --------------------------------
// Frag layout (all B-mats): value(frag fb, lane l, j) = W[n][k],
//   n = nt*16 + (l&15), k = kk*32 + (l>>4)*8 + j.
__global__ void kTrans(const float* __restrict__ h0w, const float* __restrict__ c0w,
                       const float* __restrict__ whh, const float* __restrict__ cw5,
                       const float* __restrict__ wih, const float* __restrict__ hw,
                       const float* __restrict__ polw,
                       const float* __restrict__ bih, const float* __restrict__ bhh,
                       const float* __restrict__ cb,
                       f16* __restrict__ wcb, f16* __restrict__ wgb,
                       f16* __restrict__ wib, f16* __restrict__ w5b,
                       f16* __restrict__ whb, f16* __restrict__ wpb,
                       float* __restrict__ bs2)
{
    int e = blockIdx.x*256 + threadIdx.x;
    if (e < 294912) {                    // conv3 frags: [tap][nt(16)][kk(4)]; nt<8 h0, nt>=8 c0
        int j = e & 7, l = (e >> 3) & 63, kk = (e >> 9) & 3;
        int nt = (e >> 11) & 15, tap = e >> 15;
        int c = (nt & 7)*16 + (l & 15);
        int k = kk*32 + (l >> 4)*8 + j;
        const float* src = (nt < 8) ? h0w : c0w;
        wcb[e] = (f16)src[((size_t)c*128 + k)*9 + tap];
    }
    if (e < 65536) {                     // W_hh frags [nt(32)][kk(4)]
        int j = e & 7, l = (e >> 3) & 63, fb = e >> 9;
        int nt = fb >> 2, kk = fb & 3;
        int cg = nt*16 + (l & 15), k = kk*32 + (l >> 4)*8 + j;
        wgb[e] = (f16)whh[(size_t)cg*128 + k];
    }
    if (e < 16384) {                     // W_ih replicated ext-block [nt(32)]
        int l = (e >> 3) & 63, nt = e >> 9;
        wib[e] = (f16)wih[nt*16 + (l & 15)];
    }
    if (e < 12288) {                     // hid_w frags [nt(8)][kk(3)], K=96 (taps 9..11 zero)
        int j = e & 7, l = (e >> 3) & 63, fb = e >> 9;
        int nt = fb/3, kk = fb - nt*3;
        int c = nt*16 + (l & 15), k = kk*32 + (l >> 4)*8 + j;
        whb[e] = (k < 72) ? (f16)hw[(size_t)c*72 + (k & 7)*9 + (k >> 3)] : (f16)0.f;
    }
    if (e < 4096) {                      // W5 frags [nt(2)][kk(4)], taps>=25 zero
        int j = e & 7, l = (e >> 3) & 63, fb = e >> 9;
        int nt = fb >> 2, kk = fb & 3;
        int n = nt*16 + (l & 15), k = kk*32 + (l >> 4)*8 + j;
        w5b[e] = (n < 25) ? (f16)cw5[k*25 + n] : (f16)0.f;
    }
    if (e < 2048) {                      // policy frags [kk(4)]: N=16 exactly
        int j = e & 7, l = (e >> 3) & 63, kk = e >> 9;
        int o = l & 15, k = kk*32 + (l >> 4)*8 + j;
        wpb[e] = (f16)polw[(size_t)o*128 + k];
    }
    if (e < 512) bs2[e] = bih[e] + bhh[e] + cb[0]*wih[e];
}

// ---------------- kInit: X -> hid (in LDS) -> h0,c0 (+d tail) ---------------
// block = 8x8 tile, 4 waves; now 4 blocks/CU.
__global__ __launch_bounds__(256,4) void kInit(const float* __restrict__ X,
                                               const f16* __restrict__ whb,
                                               const float* __restrict__ hidb,
                                               const f16* __restrict__ wcb,
                                               const f16* __restrict__ w5b,
                                               const float* __restrict__ h0b,
                                               const float* __restrict__ c0b,
                                               f16* __restrict__ h0out,
                                               f16* __restrict__ cc,
                                               f16* __restrict__ dout)
{
    __shared__ f16 sX[1536];
    __shared__ f16 sHalo[100*128];
    int t = threadIdx.x;
    int blk = blockIdx.x;
    int b = blk >> 6, ti = (blk >> 3) & 7, tj = blk & 7;
    int i0 = ti*8, j0 = tj*8;
    int l = t & 63, wn = t >> 6;

    for (int e = t; e < 1536; e += 256) {
        if (e < 1152) {
            int ci = e/144, pos = e - ci*144;
            int gi = i0 + pos/12 - 2, gj = j0 + pos%12 - 2;
            float xv = 0.f;
            if ((unsigned)gi < 64u && (unsigned)gj < 64u)
                xv = X[(((size_t)b*8 + ci)*64 + gi)*64 + gj];
            sX[pos*8 + ci] = (f16)xv;
        } else {
            sX[e] = (f16)0.f;
        }
    }
    __syncthreads();

    for (int mt = wn; mt < 7; mt += 4) {
        int m = mt*16 + (l & 15);
        int pi = m/10, pj = m - pi*10;
        f16x8 ax[3];
        #pragma unroll
        for (int kk = 0; kk < 3; ++kk) {
            int tap = kk*4 + (l >> 4);
            int dy = tap/3, dx = tap - dy*3;
            ax[kk] = *(const f16x8*)&sX[((pi + dy)*12 + (pj + dx))*8];
        }
        #pragma unroll
        for (int nt = 0; nt < 8; ++nt) {
            f32x4 hc = {0.f,0.f,0.f,0.f};
            #pragma unroll
            for (int kk = 0; kk < 3; ++kk)
                hc = __builtin_amdgcn_mfma_f32_16x16x32_f16(ax[kk],
                        *(const f16x8*)(whb + ((size_t)(nt*3 + kk)*64 + l)*8), hc, 0, 0, 0);
            int c = nt*16 + (l & 15);
            float bv = hidb[c];
            #pragma unroll
            for (int r = 0; r < 4; ++r) {
                int m2 = mt*16 + (l >> 4)*4 + r;
                if (m2 < 100) {
                    int pi2 = m2/10, pj2 = m2 - pi2*10;
                    int gi = i0 + pi2 - 1, gj = j0 + pj2 - 1;
                    bool inb = ((unsigned)gi < 64u && (unsigned)gj < 64u);
                    sHalo[(m2*16 + ((c >> 3) ^ (m2 & 7)))*8 + (c & 7)] =
                        inb ? (f16)(hc[r] + bv) : (f16)0.f;
                }
            }
        }
    }
    __syncthreads();

    f32x4 acc[4][4];
    #pragma unroll
    for (int mi = 0; mi < 4; ++mi)
        #pragma unroll
        for (int q = 0; q < 4; ++q) acc[mi][q] = (f32x4){0.f,0.f,0.f,0.f};

    for (int tap = 0; tap < 9; ++tap) {
        int dy = tap/3, dx = tap - dy*3;
        f16x8 a[4][4];
        #pragma unroll
        for (int mi = 0; mi < 4; ++mi) {
            int mrow = mi*16 + (l & 15);
            int pos = ((mrow >> 3) + dy)*10 + (mrow & 7) + dx;
            #pragma unroll
            for (int kk = 0; kk < 4; ++kk)
                a[mi][kk] = *(const f16x8*)&sHalo[(pos*16 + ((kk*4 + (l >> 4)) ^ (pos & 7)))*8];
        }
        #pragma unroll
        for (int q = 0; q < 4; ++q) {
            int nt = wn*4 + q;
            f16x8 bf[4];
            #pragma unroll
            for (int kk = 0; kk < 4; ++kk)
                bf[kk] = *(const f16x8*)(wcb + ((size_t)((tap*16 + nt)*4 + kk)*64 + l)*8);
            #pragma unroll
            for (int mi = 0; mi < 4; ++mi)
                #pragma unroll
                for (int kk = 0; kk < 4; ++kk)
                    acc[mi][q] = __builtin_amdgcn_mfma_f32_16x16x32_f16(a[mi][kk], bf[kk], acc[mi][q], 0, 0, 0);
        }
    }

    __syncthreads();
    f16* sH = sHalo;

    int cl = l & 15;
    bool isC = (wn >= 2);
    #pragma unroll
    for (int q = 0; q < 4; ++q) {
        int c = ((wn & 1)*4 + q)*16 + cl;
        float bv = isC ? c0b[c] : h0b[c];
        #pragma unroll
        for (int mi = 0; mi < 4; ++mi) {
            int mbase = mi*16 + (l >> 4)*4;
            if (isC) {
                f16x4 cv;
                #pragma unroll
                for (int r = 0; r < 4; ++r) cv[r] = (f16)(acc[mi][q][r] + bv);
                *(f16x4*)(cc + (size_t)blk*8192 + (size_t)c*64 + mbase) = cv;
            } else {
                #pragma unroll
                for (int r = 0; r < 4; ++r) {
                    int m = mbase + r;
                    sH[(m*16 + ((c >> 3) ^ (m & 7)))*8 + (c & 7)] = (f16)(acc[mi][q][r] + bv);
                }
            }
        }
    }
    __syncthreads();

    {
        int m0 = wn*16 + (l & 15);
        f16x8 av[4];
        #pragma unroll
        for (int kk = 0; kk < 4; ++kk)
            av[kk] = *(const f16x8*)&sH[(m0*16 + ((kk*4 + (l >> 4)) ^ (m0 & 7)))*8];
        #pragma unroll
        for (int nt = 0; nt < 2; ++nt) {
            f32x4 dc = {0.f,0.f,0.f,0.f};
            #pragma unroll
            for (int kk = 0; kk < 4; ++kk)
                dc = __builtin_amdgcn_mfma_f32_16x16x32_f16(av[kk],
                        *(const f16x8*)(w5b + ((size_t)((nt*4 + kk)*64 + l))*8), dc, 0, 0, 0);
            #pragma unroll
            for (int r = 0; r < 4; ++r) {
                int mm = wn*16 + (l >> 4)*4 + r;
                size_t gp = ((((size_t)b*64 + i0 + (mm >> 3))*64 + j0 + (mm & 7))*32) + nt*16 + (l & 15);
                dout[gp] = (f16)dc[r];
            }
        }
    }
    for (int e = t; e < 1024; e += 256) {
        int pos = e >> 4, ch = e & 15;
        f16x8 v = *(const f16x8*)&sH[(pos*16 + (ch ^ (pos & 7)))*8];
        *(f16x8*)(h0out + ((((size_t)b*64 + i0 + (pos >> 3))*64 + j0 + (pos & 7))*128) + ch*8) = v;
    }
}

// ---------------- fused LSTM step v7 ----------------------------------------
// gates = h.Whh^T + s.Wih^T + bias; s via d-halo K-extension (K=128->160).
// h_old staged coalesced into sH; a-frags from LDS; h_new overwrites sH.
// outp != nullptr => last step: fused policy conv, skip h/c/d writes.
__global__ __launch_bounds__(256,6) void kFuse(const f16* __restrict__ hin,
                                               const f16* __restrict__ din,
                                               const f16* __restrict__ wgb,
                                               const f16* __restrict__ wib,
                                               const f16* __restrict__ w5b,
                                               const f16* __restrict__ wpb,
                                               const float* __restrict__ bs2,
                                               f16* __restrict__ cc,
                                               f16* __restrict__ hout,
                                               f16* __restrict__ dout,
                                               float* __restrict__ outp)
{
    __shared__ f16 sDH[144*32];      // 12x12 d-halo, linear, 9216 B
    __shared__ f16 sH[64*128];       // h_old then h_new tile, swizzled, 16384 B
    int t = threadIdx.x;
    int blk = blockIdx.x;
    int b = blk >> 6, ti = (blk >> 3) & 7, tj = blk & 7;
    int i0 = ti*8, j0 = tj*8;
    int l = t & 63, w = t >> 6;
    int wn = w >> 1, wm = w & 1;
    int cl = l & 15;
    bool doPol = (outp != nullptr);

    // hoisted c loads (f16, latency overlapped with staging+MFMA)
    f16x4 coldv[4][2];
    #pragma unroll
    for (int q = 0; q < 4; ++q)
        #pragma unroll
        for (int mi = 0; mi < 2; ++mi) {
            int c = (wn*4 + q)*16 + cl;
            int mbase = (wm + mi*2)*16 + (l >> 4)*4;
            coldv[q][mi] = *(const f16x4*)(cc + (size_t)blk*8192 + (size_t)c*64 + mbase);
        }
    // stage own-tile h_old -> sH, fully coalesced (1KB contiguous per wave)
    for (int e = t; e < 1024; e += 256) {
        int pos = e >> 4, ch = e & 15;
        f16x8 v = *(const f16x8*)(hin + ((((size_t)b*64 + i0 + (pos >> 3))*64 + j0 + (pos & 7))*128) + ch*8);
        *(f16x8*)&sH[(pos*16 + (ch ^ (pos & 7)))*8] = v;
    }
    // stage 12x12 d-halo (zero-padded)
    for (int e = t; e < 576; e += 256) {
        int pos = e >> 2, ch = e & 3;
        int gi = i0 + pos/12 - 2, gj = j0 + pos%12 - 2;
        f16x8 v = {0,0,0,0,0,0,0,0};
        if ((unsigned)gi < 64u && (unsigned)gj < 64u)
            v = *(const f16x8*)(din + (((size_t)b*64 + gi)*64 + gj)*32 + ch*8);
        *(f16x8*)&sDH[pos*32 + ch*8] = v;
    }
    __syncthreads();

    // a-frags from LDS + K-ext frags from sDH
    f16x8 a[2][4], adh[2];
    #pragma unroll
    for (int mi = 0; mi < 2; ++mi) {
        int m = (wm + mi*2)*16 + (l & 15);
        #pragma unroll
        for (int kk = 0; kk < 4; ++kk)
            a[mi][kk] = *(const f16x8*)&sH[(m*16 + ((kk*4 + (l >> 4)) ^ (m & 7)))*8];
        int pi = m >> 3, pj = m & 7;
        f16 tmp[8];
        #pragma unroll
        for (int j = 0; j < 8; ++j) {
            int kp = (l >> 4)*8 + j;
            int kpc = (kp < 25) ? kp : 0;
            int ty = kpc/5, tx = kpc - ty*5;
            f16 v = sDH[((pi + ty)*12 + (pj + tx))*32 + kpc];
            tmp[j] = (kp < 25) ? v : (f16)0.f;
        }
        adh[mi] = *(f16x8*)tmp;
    }
    __syncthreads();          // all sH reads done before h_new overwrites

    #pragma unroll
    for (int q = 0; q < 4; ++q) {
        f32x4 acc2[2][4];            // [mi][gate]
        #pragma unroll
        for (int mi = 0; mi < 2; ++mi)
            #pragma unroll
            for (int g = 0; g < 4; ++g) acc2[mi][g] = (f32x4){0.f,0.f,0.f,0.f};
        #pragma unroll
        for (int g = 0; g < 4; ++g) {
            int nt = g*8 + wn*4 + q;
            #pragma unroll
            for (int kk = 0; kk < 4; ++kk) {
                f16x8 bf = *(const f16x8*)(wgb + ((size_t)((nt*4 + kk)*64 + l))*8);
                #pragma unroll
                for (int mi = 0; mi < 2; ++mi)
                    acc2[mi][g] = __builtin_amdgcn_mfma_f32_16x16x32_f16(a[mi][kk], bf, acc2[mi][g], 0, 0, 0);
            }
            f16x8 be = *(const f16x8*)(wib + ((size_t)(nt*64 + l))*8);
            #pragma unroll
            for (int mi = 0; mi < 2; ++mi)
                acc2[mi][g] = __builtin_amdgcn_mfma_f32_16x16x32_f16(adh[mi], be, acc2[mi][g], 0, 0, 0);
        }
        // epilogue for this channel-quad
        int c = (wn*4 + q)*16 + cl;
        float bi = bs2[c], bff = bs2[128 + c], bg = bs2[256 + c], bo = bs2[384 + c];
        #pragma unroll
        for (int mi = 0; mi < 2; ++mi) {
            int mbase = (wm + mi*2)*16 + (l >> 4)*4;
            float cn[4], hn[4];
            #pragma unroll
            for (int r = 0; r < 4; ++r) {
                float vi = acc2[mi][0][r] + bi;
                float vf = acc2[mi][1][r] + bff;
                float vg = acc2[mi][2][r] + bg;
                float vo = acc2[mi][3][r] + bo;
                float cv = sigm(vf)*(float)coldv[q][mi][r] + sigm(vi)*tanhx(vg);
                cn[r] = cv;
                hn[r] = sigm(vo)*tanhx(cv);
            }
            if (!doPol) {
                f16x4 cf;
                #pragma unroll
                for (int r = 0; r < 4; ++r) cf[r] = (f16)cn[r];
                *(f16x4*)(cc + (size_t)blk*8192 + (size_t)c*64 + mbase) = cf;
            }
            #pragma unroll
            for (int r = 0; r < 4; ++r) {
                int m = mbase + r;
                sH[(m*16 + ((c >> 3) ^ (m & 7)))*8 + (c & 7)] = (f16)hn[r];
            }
        }
    }

    __syncthreads();
    if (!doPol) {
        // d-GEMM: wave w -> M-tile w
        int m0 = w*16 + (l & 15);
        f16x8 av[4];
        #pragma unroll
        for (int kk = 0; kk < 4; ++kk)
            av[kk] = *(const f16x8*)&sH[(m0*16 + ((kk*4 + (l >> 4)) ^ (m0 & 7)))*8];
        #pragma unroll
        for (int nt = 0; nt < 2; ++nt) {
            f32x4 dc = {0.f,0.f,0.f,0.f};
            #pragma unroll
            for (int kk = 0; kk < 4; ++kk)
                dc = __builtin_amdgcn_mfma_f32_16x16x32_f16(av[kk],
                        *(const f16x8*)(w5b + ((size_t)((nt*4 + kk)*64 + l))*8), dc, 0, 0, 0);
            #pragma unroll
            for (int r = 0; r < 4; ++r) {
                int mm = w*16 + (l >> 4)*4 + r;
                size_t gp = ((((size_t)b*64 + i0 + (mm >> 3))*64 + j0 + (mm & 7))*32) + nt*16 + (l & 15);
                dout[gp] = (f16)dc[r];
            }
        }
        // vectorized h store from sH
        for (int e = t; e < 1024; e += 256) {
            int pos = e >> 4, ch = e & 15;
            f16x8 v = *(const f16x8*)&sH[(pos*16 + (ch ^ (pos & 7)))*8];
            *(f16x8*)(hout + ((((size_t)b*64 + i0 + (pos >> 3))*64 + j0 + (pos & 7))*128) + ch*8) = v;
        }
    } else {
        // policy GEMM: wave w -> M-tile w, N=16 (o = l&15), K=128 from sH
        int m0 = w*16 + (l & 15);
        f16x8 av[4];
        #pragma unroll
        for (int kk = 0; kk < 4; ++kk)
            av[kk] = *(const f16x8*)&sH[(m0*16 + ((kk*4 + (l >> 4)) ^ (m0 & 7)))*8];
        f32x4 pc = {0.f,0.f,0.f,0.f};
        #pragma unroll
        for (int kk = 0; kk < 4; ++kk)
            pc = __builtin_amdgcn_mfma_f32_16x16x32_f16(av[kk],
                    *(const f16x8*)(wpb + ((size_t)(kk*64 + l))*8), pc, 0, 0, 0);
        int o = l & 15;
        #pragma unroll
        for (int r = 0; r < 4; ++r) {
            int mm = w*16 + (l >> 4)*4 + r;
            outp[(((size_t)b*16 + o)*4096) + (size_t)(i0 + (mm >> 3))*64 + j0 + (mm & 7)] = pc[r];
        }
    }
}

extern "C" void kernel_launch(void* const* d_in, const int* in_sizes, int n_in,
                              void* d_out, int out_size, void* d_ws, size_t ws_size,
                              hipStream_t stream) {
    const float* X      = (const float*)d_in[0];
    const float* hid_w  = (const float*)d_in[1];
    const float* hid_b  = (const float*)d_in[2];
    const float* h0_w   = (const float*)d_in[3];
    const float* h0_b   = (const float*)d_in[4];
    const float* c0_w   = (const float*)d_in[5];
    const float* c0_b   = (const float*)d_in[6];
    const float* conv_w = (const float*)d_in[7];
    const float* conv_b = (const float*)d_in[8];
    const float* W_ih   = (const float*)d_in[9];
    const float* W_hh   = (const float*)d_in[10];
    const float* b_ih   = (const float*)d_in[11];
    const float* b_hh   = (const float*)d_in[12];
    const float* pol_w  = (const float*)d_in[13];
    // d_in[14] = k (=10); steps = k-1 = 9 hard-coded

    if (ws_size < WS_BYTES) return;   // fail-visible guard

    char* wsb = (char*)d_ws;
    f16*   CC  = (f16*)  (wsb + OB_CC);
    f16*   HA  = (f16*)  (wsb + OB_HA);
    f16*   HB  = (f16*)  (wsb + OB_HB);
    f16*   DA  = (f16*)  (wsb + OB_DA);
    f16*   DB  = (f16*)  (wsb + OB_DB);
    f16*   WCB = (f16*)  (wsb + OB_WCB);
    f16*   WGB = (f16*)  (wsb + OB_WGB);
    f16*   WIB = (f16*)  (wsb + OB_WIB);
    f16*   W5B = (f16*)  (wsb + OB_W5B);
    f16*   WHB = (f16*)  (wsb + OB_WHB);
    f16*   WPB = (f16*)  (wsb + OB_WPB);
    float* BS2 = (float*)(wsb + OB_BS2);

    kTrans<<<1152, 256, 0, stream>>>(h0_w, c0_w, W_hh, conv_w, W_ih, hid_w, pol_w,
                                     b_ih, b_hh, conv_b,
                                     WCB, WGB, WIB, W5B, WHB, WPB, BS2);
    kInit<<<2048, 256, 0, stream>>>(X, WHB, hid_b, WCB, W5B, h0_b, c0_b, HA, CC, DA);
    for (int st = 0; st < 9; ++st) {
        const f16* hin = (st & 1) ? HB : HA;
        const f16* din = (st & 1) ? DB : DA;
        f16* hout      = (st & 1) ? HA : HB;
        f16* dout      = (st & 1) ? DA : DB;
        float* outp    = (st == 8) ? (float*)d_out : nullptr;
        kFuse<<<2048, 256, 0, stream>>>(hin, din, WGB, WIB, W5B, WPB, BS2,
                                        CC, hout, dout, outp);
    }
}

// Round 12
// 797.637 us; speedup vs baseline: 2.1465x; 2.1465x over previous
//
#include <hip/hip_runtime.h>
#include <math.h>

// GPPN fused v8: B=32, L_H=128, MAZE=64, F=5, OUT=16, k=10 (9 LSTM steps)
// R10 backbone (launch bounds REVERTED to proven values after R11's spill storm:
// (256,4)/(256,6) forced VGPR 88->64 + 240MB scratch FETCH) + R11's coalesced
// h-staging/LDS a-frags in kFuse as the single isolated change vs R10.

typedef _Float16 f16;
typedef _Float16 f16x4 __attribute__((ext_vector_type(4)));
typedef _Float16 f16x8 __attribute__((ext_vector_type(8)));
typedef float    f32x4 __attribute__((ext_vector_type(4)));

#define NB 32
#define HWD 64

// ---- workspace byte offsets
#define OB_CC    ((size_t)0)            // f16 c [blk][128][64]   32 MB
#define OB_HA    ((size_t)33554432)     // f16 h ping             32 MB
#define OB_HB    ((size_t)67108864)     // f16 h pong             32 MB
#define OB_DA    ((size_t)100663296)    // f16 d ping             8 MB
#define OB_DB    ((size_t)109051904)    // f16 d pong             8 MB
#define OB_WCB   ((size_t)117440512)    // f16 conv3 B-frags      589824 B
#define OB_WGB   ((size_t)118030336)    // f16 W_hh B-frags       131072 B
#define OB_WIB   ((size_t)118161408)    // f16 W_ih replicated    32768 B
#define OB_W5B   ((size_t)118194176)    // f16 W5 B-frags         8192 B
#define OB_WHB   ((size_t)118202368)    // f16 hid_w B-frags K=96 24576 B
#define OB_WPB   ((size_t)118226944)    // f16 policy B-frags     4096 B
#define OB_BS2   ((size_t)118231040)    // f32 b_ih+b_hh+cb*W_ih  2048 B
#define WS_BYTES ((size_t)118233088)

__device__ __forceinline__ float sigm(float x){ return 1.f/(1.f+__expf(-x)); }
__device__ __forceinline__ float tanhx(float x){ return 1.f - 2.f/(1.f+__expf(2.f*x)); }

// ---------------- one-time weight transforms --------------------------------
// Frag layout (all B-mats): value(frag fb, lane l, j) = W[n][k],
//   n = nt*16 + (l&15), k = kk*32 + (l>>4)*8 + j.
__global__ void kTrans(const float* __restrict__ h0w, const float* __restrict__ c0w,
                       const float* __restrict__ whh, const float* __restrict__ cw5,
                       const float* __restrict__ wih, const float* __restrict__ hw,
                       const float* __restrict__ polw,
                       const float* __restrict__ bih, const float* __restrict__ bhh,
                       const float* __restrict__ cb,
                       f16* __restrict__ wcb, f16* __restrict__ wgb,
                       f16* __restrict__ wib, f16* __restrict__ w5b,
                       f16* __restrict__ whb, f16* __restrict__ wpb,
                       float* __restrict__ bs2)
{
    int e = blockIdx.x*256 + threadIdx.x;
    if (e < 294912) {                    // conv3 frags: [tap][nt(16)][kk(4)]; nt<8 h0, nt>=8 c0
        int j = e & 7, l = (e >> 3) & 63, kk = (e >> 9) & 3;
        int nt = (e >> 11) & 15, tap = e >> 15;
        int c = (nt & 7)*16 + (l & 15);
        int k = kk*32 + (l >> 4)*8 + j;
        const float* src = (nt < 8) ? h0w : c0w;
        wcb[e] = (f16)src[((size_t)c*128 + k)*9 + tap];
    }
    if (e < 65536) {                     // W_hh frags [nt(32)][kk(4)]
        int j = e & 7, l = (e >> 3) & 63, fb = e >> 9;
        int nt = fb >> 2, kk = fb & 3;
        int cg = nt*16 + (l & 15), k = kk*32 + (l >> 4)*8 + j;
        wgb[e] = (f16)whh[(size_t)cg*128 + k];
    }
    if (e < 16384) {                     // W_ih replicated ext-block [nt(32)]
        int l = (e >> 3) & 63, nt = e >> 9;
        wib[e] = (f16)wih[nt*16 + (l & 15)];
    }
    if (e < 12288) {                     // hid_w frags [nt(8)][kk(3)], K=96 (taps 9..11 zero)
        int j = e & 7, l = (e >> 3) & 63, fb = e >> 9;
        int nt = fb/3, kk = fb - nt*3;
        int c = nt*16 + (l & 15), k = kk*32 + (l >> 4)*8 + j;
        whb[e] = (k < 72) ? (f16)hw[(size_t)c*72 + (k & 7)*9 + (k >> 3)] : (f16)0.f;
    }
    if (e < 4096) {                      // W5 frags [nt(2)][kk(4)], taps>=25 zero
        int j = e & 7, l = (e >> 3) & 63, fb = e >> 9;
        int nt = fb >> 2, kk = fb & 3;
        int n = nt*16 + (l & 15), k = kk*32 + (l >> 4)*8 + j;
        w5b[e] = (n < 25) ? (f16)cw5[k*25 + n] : (f16)0.f;
    }
    if (e < 2048) {                      // policy frags [kk(4)]: N=16 exactly
        int j = e & 7, l = (e >> 3) & 63, kk = e >> 9;
        int o = l & 15, k = kk*32 + (l >> 4)*8 + j;
        wpb[e] = (f16)polw[(size_t)o*128 + k];
    }
    if (e < 512) bs2[e] = bih[e] + bhh[e] + cb[0]*wih[e];
}

// ---------------- kInit: X -> hid (in LDS) -> h0,c0 (+d tail) ---------------
// block = 8x8 tile, 4 waves; (256,2): proven no-spill (VGPR 88).
__global__ __launch_bounds__(256,2) void kInit(const float* __restrict__ X,
                                               const f16* __restrict__ whb,
                                               const float* __restrict__ hidb,
                                               const f16* __restrict__ wcb,
                                               const f16* __restrict__ w5b,
                                               const float* __restrict__ h0b,
                                               const float* __restrict__ c0b,
                                               f16* __restrict__ h0out,
                                               f16* __restrict__ cc,
                                               f16* __restrict__ dout)
{
    __shared__ f16 sX[1536];
    __shared__ f16 sHalo[100*128];
    int t = threadIdx.x;
    int blk = blockIdx.x;
    int b = blk >> 6, ti = (blk >> 3) & 7, tj = blk & 7;
    int i0 = ti*8, j0 = tj*8;
    int l = t & 63, wn = t >> 6;

    for (int e = t; e < 1536; e += 256) {
        if (e < 1152) {
            int ci = e/144, pos = e - ci*144;
            int gi = i0 + pos/12 - 2, gj = j0 + pos%12 - 2;
            float xv = 0.f;
            if ((unsigned)gi < 64u && (unsigned)gj < 64u)
                xv = X[(((size_t)b*8 + ci)*64 + gi)*64 + gj];
            sX[pos*8 + ci] = (f16)xv;
        } else {
            sX[e] = (f16)0.f;
        }
    }
    __syncthreads();

    for (int mt = wn; mt < 7; mt += 4) {
        int m = mt*16 + (l & 15);
        int pi = m/10, pj = m - pi*10;
        f16x8 ax[3];
        #pragma unroll
        for (int kk = 0; kk < 3; ++kk) {
            int tap = kk*4 + (l >> 4);
            int dy = tap/3, dx = tap - dy*3;
            ax[kk] = *(const f16x8*)&sX[((pi + dy)*12 + (pj + dx))*8];
        }
        #pragma unroll
        for (int nt = 0; nt < 8; ++nt) {
            f32x4 hc = {0.f,0.f,0.f,0.f};
            #pragma unroll
            for (int kk = 0; kk < 3; ++kk)
                hc = __builtin_amdgcn_mfma_f32_16x16x32_f16(ax[kk],
                        *(const f16x8*)(whb + ((size_t)(nt*3 + kk)*64 + l)*8), hc, 0, 0, 0);
            int c = nt*16 + (l & 15);
            float bv = hidb[c];
            #pragma unroll
            for (int r = 0; r < 4; ++r) {
                int m2 = mt*16 + (l >> 4)*4 + r;
                if (m2 < 100) {
                    int pi2 = m2/10, pj2 = m2 - pi2*10;
                    int gi = i0 + pi2 - 1, gj = j0 + pj2 - 1;
                    bool inb = ((unsigned)gi < 64u && (unsigned)gj < 64u);
                    sHalo[(m2*16 + ((c >> 3) ^ (m2 & 7)))*8 + (c & 7)] =
                        inb ? (f16)(hc[r] + bv) : (f16)0.f;
                }
            }
        }
    }
    __syncthreads();

    f32x4 acc[4][4];
    #pragma unroll
    for (int mi = 0; mi < 4; ++mi)
        #pragma unroll
        for (int q = 0; q < 4; ++q) acc[mi][q] = (f32x4){0.f,0.f,0.f,0.f};

    for (int tap = 0; tap < 9; ++tap) {
        int dy = tap/3, dx = tap - dy*3;
        f16x8 a[4][4];
        #pragma unroll
        for (int mi = 0; mi < 4; ++mi) {
            int mrow = mi*16 + (l & 15);
            int pos = ((mrow >> 3) + dy)*10 + (mrow & 7) + dx;
            #pragma unroll
            for (int kk = 0; kk < 4; ++kk)
                a[mi][kk] = *(const f16x8*)&sHalo[(pos*16 + ((kk*4 + (l >> 4)) ^ (pos & 7)))*8];
        }
        #pragma unroll
        for (int q = 0; q < 4; ++q) {
            int nt = wn*4 + q;
            f16x8 bf[4];
            #pragma unroll
            for (int kk = 0; kk < 4; ++kk)
                bf[kk] = *(const f16x8*)(wcb + ((size_t)((tap*16 + nt)*4 + kk)*64 + l)*8);
            #pragma unroll
            for (int mi = 0; mi < 4; ++mi)
                #pragma unroll
                for (int kk = 0; kk < 4; ++kk)
                    acc[mi][q] = __builtin_amdgcn_mfma_f32_16x16x32_f16(a[mi][kk], bf[kk], acc[mi][q], 0, 0, 0);
        }
    }

    __syncthreads();
    f16* sH = sHalo;

    int cl = l & 15;
    bool isC = (wn >= 2);
    #pragma unroll
    for (int q = 0; q < 4; ++q) {
        int c = ((wn & 1)*4 + q)*16 + cl;
        float bv = isC ? c0b[c] : h0b[c];
        #pragma unroll
        for (int mi = 0; mi < 4; ++mi) {
            int mbase = mi*16 + (l >> 4)*4;
            if (isC) {
                f16x4 cv;
                #pragma unroll
                for (int r = 0; r < 4; ++r) cv[r] = (f16)(acc[mi][q][r] + bv);
                *(f16x4*)(cc + (size_t)blk*8192 + (size_t)c*64 + mbase) = cv;
            } else {
                #pragma unroll
                for (int r = 0; r < 4; ++r) {
                    int m = mbase + r;
                    sH[(m*16 + ((c >> 3) ^ (m & 7)))*8 + (c & 7)] = (f16)(acc[mi][q][r] + bv);
                }
            }
        }
    }
    __syncthreads();

    {
        int m0 = wn*16 + (l & 15);
        f16x8 av[4];
        #pragma unroll
        for (int kk = 0; kk < 4; ++kk)
            av[kk] = *(const f16x8*)&sH[(m0*16 + ((kk*4 + (l >> 4)) ^ (m0 & 7)))*8];
        #pragma unroll
        for (int nt = 0; nt < 2; ++nt) {
            f32x4 dc = {0.f,0.f,0.f,0.f};
            #pragma unroll
            for (int kk = 0; kk < 4; ++kk)
                dc = __builtin_amdgcn_mfma_f32_16x16x32_f16(av[kk],
                        *(const f16x8*)(w5b + ((size_t)((nt*4 + kk)*64 + l))*8), dc, 0, 0, 0);
            #pragma unroll
            for (int r = 0; r < 4; ++r) {
                int mm = wn*16 + (l >> 4)*4 + r;
                size_t gp = ((((size_t)b*64 + i0 + (mm >> 3))*64 + j0 + (mm & 7))*32) + nt*16 + (l & 15);
                dout[gp] = (f16)dc[r];
            }
        }
    }
    for (int e = t; e < 1024; e += 256) {
        int pos = e >> 4, ch = e & 15;
        f16x8 v = *(const f16x8*)&sH[(pos*16 + (ch ^ (pos & 7)))*8];
        *(f16x8*)(h0out + ((((size_t)b*64 + i0 + (pos >> 3))*64 + j0 + (pos & 7))*128) + ch*8) = v;
    }
}

// ---------------- fused LSTM step v8 ----------------------------------------
// gates = h.Whh^T + s.Wih^T + bias; s via d-halo K-extension (K=128->160).
// h_old staged coalesced into sH; a-frags from LDS; h_new overwrites sH.
// (256,4): proven no-spill cap. outp != nullptr => last step w/ fused policy.
__global__ __launch_bounds__(256,4) void kFuse(const f16* __restrict__ hin,
                                               const f16* __restrict__ din,
                                               const f16* __restrict__ wgb,
                                               const f16* __restrict__ wib,
                                               const f16* __restrict__ w5b,
                                               const f16* __restrict__ wpb,
                                               const float* __restrict__ bs2,
                                               f16* __restrict__ cc,
                                               f16* __restrict__ hout,
                                               f16* __restrict__ dout,
                                               float* __restrict__ outp)
{
    __shared__ f16 sDH[144*32];      // 12x12 d-halo, linear, 9216 B
    __shared__ f16 sH[64*128];       // h_old then h_new tile, swizzled, 16384 B
    int t = threadIdx.x;
    int blk = blockIdx.x;
    int b = blk >> 6, ti = (blk >> 3) & 7, tj = blk & 7;
    int i0 = ti*8, j0 = tj*8;
    int l = t & 63, w = t >> 6;
    int wn = w >> 1, wm = w & 1;
    int cl = l & 15;
    bool doPol = (outp != nullptr);

    // hoisted c loads (f16, latency overlapped with staging+MFMA)
    f16x4 coldv[4][2];
    #pragma unroll
    for (int q = 0; q < 4; ++q)
        #pragma unroll
        for (int mi = 0; mi < 2; ++mi) {
            int c = (wn*4 + q)*16 + cl;
            int mbase = (wm + mi*2)*16 + (l >> 4)*4;
            coldv[q][mi] = *(const f16x4*)(cc + (size_t)blk*8192 + (size_t)c*64 + mbase);
        }
    // stage own-tile h_old -> sH, fully coalesced (1KB contiguous per wave)
    for (int e = t; e < 1024; e += 256) {
        int pos = e >> 4, ch = e & 15;
        f16x8 v = *(const f16x8*)(hin + ((((size_t)b*64 + i0 + (pos >> 3))*64 + j0 + (pos & 7))*128) + ch*8);
        *(f16x8*)&sH[(pos*16 + (ch ^ (pos & 7)))*8] = v;
    }
    // stage 12x12 d-halo (zero-padded)
    for (int e = t; e < 576; e += 256) {
        int pos = e >> 2, ch = e & 3;
        int gi = i0 + pos/12 - 2, gj = j0 + pos%12 - 2;
        f16x8 v = {0,0,0,0,0,0,0,0};
        if ((unsigned)gi < 64u && (unsigned)gj < 64u)
            v = *(const f16x8*)(din + (((size_t)b*64 + gi)*64 + gj)*32 + ch*8);
        *(f16x8*)&sDH[pos*32 + ch*8] = v;
    }
    __syncthreads();

    // a-frags from LDS + K-ext frags from sDH
    f16x8 a[2][4], adh[2];
    #pragma unroll
    for (int mi = 0; mi < 2; ++mi) {
        int m = (wm + mi*2)*16 + (l & 15);
        #pragma unroll
        for (int kk = 0; kk < 4; ++kk)
            a[mi][kk] = *(const f16x8*)&sH[(m*16 + ((kk*4 + (l >> 4)) ^ (m & 7)))*8];
        int pi = m >> 3, pj = m & 7;
        f16 tmp[8];
        #pragma unroll
        for (int j = 0; j < 8; ++j) {
            int kp = (l >> 4)*8 + j;
            int kpc = (kp < 25) ? kp : 0;
            int ty = kpc/5, tx = kpc - ty*5;
            f16 v = sDH[((pi + ty)*12 + (pj + tx))*32 + kpc];
            tmp[j] = (kp < 25) ? v : (f16)0.f;
        }
        adh[mi] = *(f16x8*)tmp;
    }
    __syncthreads();          // all sH reads done before h_new overwrites

    #pragma unroll
    for (int q = 0; q < 4; ++q) {
        f32x4 acc2[2][4];            // [mi][gate]
        #pragma unroll
        for (int mi = 0; mi < 2; ++mi)
            #pragma unroll
            for (int g = 0; g < 4; ++g) acc2[mi][g] = (f32x4){0.f,0.f,0.f,0.f};
        #pragma unroll
        for (int g = 0; g < 4; ++g) {
            int nt = g*8 + wn*4 + q;
            #pragma unroll
            for (int kk = 0; kk < 4; ++kk) {
                f16x8 bf = *(const f16x8*)(wgb + ((size_t)((nt*4 + kk)*64 + l))*8);
                #pragma unroll
                for (int mi = 0; mi < 2; ++mi)
                    acc2[mi][g] = __builtin_amdgcn_mfma_f32_16x16x32_f16(a[mi][kk], bf, acc2[mi][g], 0, 0, 0);
            }
            f16x8 be = *(const f16x8*)(wib + ((size_t)(nt*64 + l))*8);
            #pragma unroll
            for (int mi = 0; mi < 2; ++mi)
                acc2[mi][g] = __builtin_amdgcn_mfma_f32_16x16x32_f16(adh[mi], be, acc2[mi][g], 0, 0, 0);
        }
        // epilogue for this channel-quad
        int c = (wn*4 + q)*16 + cl;
        float bi = bs2[c], bff = bs2[128 + c], bg = bs2[256 + c], bo = bs2[384 + c];
        #pragma unroll
        for (int mi = 0; mi < 2; ++mi) {
            int mbase = (wm + mi*2)*16 + (l >> 4)*4;
            float cn[4], hn[4];
            #pragma unroll
            for (int r = 0; r < 4; ++r) {
                float vi = acc2[mi][0][r] + bi;
                float vf = acc2[mi][1][r] + bff;
                float vg = acc2[mi][2][r] + bg;
                float vo = acc2[mi][3][r] + bo;
                float cv = sigm(vf)*(float)coldv[q][mi][r] + sigm(vi)*tanhx(vg);
                cn[r] = cv;
                hn[r] = sigm(vo)*tanhx(cv);
            }
            if (!doPol) {
                f16x4 cf;
                #pragma unroll
                for (int r = 0; r < 4; ++r) cf[r] = (f16)cn[r];
                *(f16x4*)(cc + (size_t)blk*8192 + (size_t)c*64 + mbase) = cf;
            }
            #pragma unroll
            for (int r = 0; r < 4; ++r) {
                int m = mbase + r;
                sH[(m*16 + ((c >> 3) ^ (m & 7)))*8 + (c & 7)] = (f16)hn[r];
            }
        }
    }

    __syncthreads();
    if (!doPol) {
        // d-GEMM: wave w -> M-tile w
        int m0 = w*16 + (l & 15);
        f16x8 av[4];
        #pragma unroll
        for (int kk = 0; kk < 4; ++kk)
            av[kk] = *(const f16x8*)&sH[(m0*16 + ((kk*4 + (l >> 4)) ^ (m0 & 7)))*8];
        #pragma unroll
        for (int nt = 0; nt < 2; ++nt) {
            f32x4 dc = {0.f,0.f,0.f,0.f};
            #pragma unroll
            for (int kk = 0; kk < 4; ++kk)
                dc = __builtin_amdgcn_mfma_f32_16x16x32_f16(av[kk],
                        *(const f16x8*)(w5b + ((size_t)((nt*4 + kk)*64 + l))*8), dc, 0, 0, 0);
            #pragma unroll
            for (int r = 0; r < 4; ++r) {
                int mm = w*16 + (l >> 4)*4 + r;
                size_t gp = ((((size_t)b*64 + i0 + (mm >> 3))*64 + j0 + (mm & 7))*32) + nt*16 + (l & 15);
                dout[gp] = (f16)dc[r];
            }
        }
        // vectorized h store from sH
        for (int e = t; e < 1024; e += 256) {
            int pos = e >> 4, ch = e & 15;
            f16x8 v = *(const f16x8*)&sH[(pos*16 + (ch ^ (pos & 7)))*8];
            *(f16x8*)(hout + ((((size_t)b*64 + i0 + (pos >> 3))*64 + j0 + (pos & 7))*128) + ch*8) = v;
        }
    } else {
        // policy GEMM: wave w -> M-tile w, N=16 (o = l&15), K=128 from sH
        int m0 = w*16 + (l & 15);
        f16x8 av[4];
        #pragma unroll
        for (int kk = 0; kk < 4; ++kk)
            av[kk] = *(const f16x8*)&sH[(m0*16 + ((kk*4 + (l >> 4)) ^ (m0 & 7)))*8];
        f32x4 pc = {0.f,0.f,0.f,0.f};
        #pragma unroll
        for (int kk = 0; kk < 4; ++kk)
            pc = __builtin_amdgcn_mfma_f32_16x16x32_f16(av[kk],
                    *(const f16x8*)(wpb + ((size_t)(kk*64 + l))*8), pc, 0, 0, 0);
        int o = l & 15;
        #pragma unroll
        for (int r = 0; r < 4; ++r) {
            int mm = w*16 + (l >> 4)*4 + r;
            outp[(((size_t)b*16 + o)*4096) + (size_t)(i0 + (mm >> 3))*64 + j0 + (mm & 7)] = pc[r];
        }
    }
}

extern "C" void kernel_launch(void* const* d_in, const int* in_sizes, int n_in,
                              void* d_out, int out_size, void* d_ws, size_t ws_size,
                              hipStream_t stream) {
    const float* X      = (const float*)d_in[0];
    const float* hid_w  = (const float*)d_in[1];
    const float* hid_b  = (const float*)d_in[2];
    const float* h0_w   = (const float*)d_in[3];
    const float* h0_b   = (const float*)d_in[4];
    const float* c0_w   = (const float*)d_in[5];
    const float* c0_b   = (const float*)d_in[6];
    const float* conv_w = (const float*)d_in[7];
    const float* conv_b = (const float*)d_in[8];
    const float* W_ih   = (const float*)d_in[9];
    const float* W_hh   = (const float*)d_in[10];
    const float* b_ih   = (const float*)d_in[11];
    const float* b_hh   = (const float*)d_in[12];
    const float* pol_w  = (const float*)d_in[13];
    // d_in[14] = k (=10); steps = k-1 = 9 hard-coded

    if (ws_size < WS_BYTES) return;   // fail-visible guard

    char* wsb = (char*)d_ws;
    f16*   CC  = (f16*)  (wsb + OB_CC);
    f16*   HA  = (f16*)  (wsb + OB_HA);
    f16*   HB  = (f16*)  (wsb + OB_HB);
    f16*   DA  = (f16*)  (wsb + OB_DA);
    f16*   DB  = (f16*)  (wsb + OB_DB);
    f16*   WCB = (f16*)  (wsb + OB_WCB);
    f16*   WGB = (f16*)  (wsb + OB_WGB);
    f16*   WIB = (f16*)  (wsb + OB_WIB);
    f16*   W5B = (f16*)  (wsb + OB_W5B);
    f16*   WHB = (f16*)  (wsb + OB_WHB);
    f16*   WPB = (f16*)  (wsb + OB_WPB);
    float* BS2 = (float*)(wsb + OB_BS2);

    kTrans<<<1152, 256, 0, stream>>>(h0_w, c0_w, W_hh, conv_w, W_ih, hid_w, pol_w,
                                     b_ih, b_hh, conv_b,
                                     WCB, WGB, WIB, W5B, WHB, WPB, BS2);
    kInit<<<2048, 256, 0, stream>>>(X, WHB, hid_b, WCB, W5B, h0_b, c0_b, HA, CC, DA);
    for (int st = 0; st < 9; ++st) {
        const f16* hin = (st & 1) ? HB : HA;
        const f16* din = (st & 1) ? DB : DA;
        f16* hout      = (st & 1) ? HA : HB;
        f16* dout      = (st & 1) ? DA : DB;
        float* outp    = (st == 8) ? (float*)d_out : nullptr;
        kFuse<<<2048, 256, 0, stream>>>(hin, din, WGB, WIB, W5B, WPB, BS2,
                                        CC, hout, dout, outp);
    }
}